// Round 23
// baseline (33.388 us; speedup 1.0000x reference)
//
#include <hip/hip_runtime.h>

// B=64, H=W=512, K=7, VALID conv -> 506x506.
// v23: MSHR-volume attack. Model (fits all 12 clean kernels): per-CU
// outstanding-miss capacity x latency caps READ bw at ~10 GB/s/CU
// (fill kernel's store-only stream: 6.7 TB/s; our read streams: ~3).
// v17 tracked ~488 KB/CU (wave halo re-reads miss L1, eat MSHRs even on
// L2 hits). Fix: stage each 64x32 tile's input ONCE per block in LDS via
// global_load_lds (wave-linear dest, zero VGPR), waves read halo from LDS.
// Tracked volume 488->325 KB/CU; x-overfetch 48->40B per window.
// All staging loads in-bounds by shifted tiling (no clamps). Compute
// reads = contiguous-per-wave float4 (max-rate LDS pattern; compiler's
// fine-grained lgkmcnt is good -- m97). No launch_bounds cap (v3/v4/v7).
#define HW    512
#define OW    506
#define SROWS 38                  // staged rows: 32 outputs + 6 halo
#define SF4   66                  // staged float4 per row (264 floats)
#define NCH   (SROWS * SF4)       // 2508 chunks = 40128 B LDS -> 4 blocks/CU

typedef float vf4 __attribute__((ext_vector_type(4)));

template<int SH>
__device__ __forceinline__ void row_fma(int ir, const vf4 (&b)[3],
                                        const float (&wv)[49],
                                        float (&acc)[32]) {
#pragma unroll
    for (int kr = 0; kr < 7; ++kr) {
        const int s = ir - kr;               // constant after caller unroll
        if (s >= 0 && s < 8) {
#pragma unroll
            for (int kc = 0; kc < 7; ++kc) {
                const float wk = wv[kr * 7 + kc];
#pragma unroll
                for (int j = 0; j < 4; ++j) {
                    const int e = SH + kc + j;          // 0..11, constant
                    acc[s * 4 + j] = fmaf(wk, b[e >> 2][e & 3], acc[s * 4 + j]);
                }
            }
        }
    }
}

template<int SH>
__device__ __forceinline__ void conv_lds(const float* __restrict__ lds,
                                         int w, int lane,
                                         const float (&wv)[49],
                                         float (&acc)[32]) {
    // wave w computes rows 8w..8w+7 from staged rows 8w..8w+13.
    // Per row: 3 contiguous float4 reads (lanes at 16B stride -> 1024B
    // contiguous per instruction = max-rate LDS pattern, no conflicts).
    const float* rp0 = lds + (8 * w) * (SF4 * 4) + 4 * lane;
#pragma unroll
    for (int ir = 0; ir < 14; ++ir) {
        const float* rp = rp0 + ir * (SF4 * 4);
        vf4 b[3];
        b[0] = *reinterpret_cast<const vf4*>(rp);
        b[1] = *reinterpret_cast<const vf4*>(rp + 4);
        b[2] = *reinterpret_cast<const vf4*>(rp + 8);
        row_fma<SH>(ir, b, wv, acc);
    }
}

__global__ __launch_bounds__(256) void conv7x7_v23(
    const float* __restrict__ in,      // [64][512][512]
    const float* __restrict__ weight,  // [7][7]
    const float* __restrict__ bias,    // [1]
    float* __restrict__ out)           // [64][506][506]
{
    __shared__ vf4 tile[NCH];          // 40128 B

    const int tid  = threadIdx.x;
    const int lane = tid & 63;
    const int w    = tid >> 6;
    const int bx   = blockIdx.x;                // 0 or 1
    const int x0   = bx ? 250 : 0;              // output tiles 0..255 / 250..505
    const int xs   = bx ? 248 : 0;              // staged col base (16B aligned)
    const int y0   = min((int)blockIdx.y * 32, OW - 32);  // shifted last tile
    const int b    = blockIdx.z;

    // ---- weights + bias -> SGPRs (uniform, statically indexed) ----
    float wv[49];
#pragma unroll
    for (int i = 0; i < 49; ++i)
        wv[i] = __uint_as_float(__builtin_amdgcn_readfirstlane(__float_as_uint(weight[i])));
    const float bv = __uint_as_float(__builtin_amdgcn_readfirstlane(__float_as_uint(bias[0])));

    // staged region origin: rows y0..y0+37 (<=511), cols xs..xs+263 (<=511)
    const float* __restrict__ ib = in + (size_t)b * (HW * HW) + y0 * HW + xs;

    // ---- stage 38 x 264 floats via global_load_lds width-16 ----
    // chunk q = tid + 256k: LDS dest = tile + q (linear in lane, matches
    // wave-uniform-base + lane*16); global src per-lane = row q/66, col4 q%66.
#pragma unroll
    for (int k = 0; k < 10; ++k) {
        const int q = tid + (k << 8);
        if (q < NCH) {
            const int r  = q / SF4;             // magic-mul division
            const int c4 = q - r * SF4;
            __builtin_amdgcn_global_load_lds(
                (const __attribute__((address_space(1))) void*)(ib + r * HW + 4 * c4),
                (__attribute__((address_space(3))) void*)(tile + q),
                16, 0, 0);
        }
    }
    __syncthreads();                            // drains vmcnt, then barrier

    // ---- compute: wave w owns rows 8w..8w+7; lane owns 4 cols ----
    float acc[32];
#pragma unroll
    for (int i = 0; i < 32; ++i) acc[i] = bv;   // bias folded into init

    const float* lds = reinterpret_cast<const float*>(tile);
    if (bx == 0) conv_lds<0>(lds, w, lane, wv, acc);   // uniform SGPR branch
    else         conv_lds<2>(lds, w, lane, wv, acc);

    // ---- store: 8 rows x 4 cols, two float2 per row, unguarded ----
    const int cb = x0 + 4 * lane;               // first output col (<=502)
    const int yb = y0 + 8 * w;
    float* __restrict__ outb = out + (size_t)b * (OW * OW);
#pragma unroll
    for (int s = 0; s < 8; ++s) {
        float* orow = outb + (size_t)(yb + s) * OW + cb;   // cb even -> 8B aligned
        *reinterpret_cast<float2*>(orow) =
            make_float2(acc[s * 4 + 0], acc[s * 4 + 1]);
        *reinterpret_cast<float2*>(orow + 2) =
            make_float2(acc[s * 4 + 2], acc[s * 4 + 3]);
    }
}

extern "C" void kernel_launch(void* const* d_in, const int* in_sizes, int n_in,
                              void* d_out, int out_size, void* d_ws, size_t ws_size,
                              hipStream_t stream) {
    const float* enc_x  = (const float*)d_in[0];
    const float* weight = (const float*)d_in[1];
    const float* bias   = (const float*)d_in[2];
    float* outp         = (float*)d_out;

    // x: 2 overlapping 256-col tiles; y: 16 tiles of 32 rows (last shifted);
    // z: 64 images. 2048 blocks, 4 concurrent/CU by LDS.
    dim3 grid(2, 16, 64);
    dim3 block(256);
    hipLaunchKernelGGL(conv7x7_v23, grid, block, 0, stream,
                       enc_x, weight, bias, outp);
}

// Round 24
// 33.376 us; speedup vs baseline: 1.0004x; 1.0004x over previous
//
#include <hip/hip_runtime.h>

// B=64, H=W=512, K=7, VALID conv -> 506x506.
// v24 = v17 engine (asm-pinned 4-row counted-vmcnt pipeline, 4x8 tile,
// guard-free shifted tiling) wrapped in a PLAIN 2-image loop per block.
// Suspect ledger after 13 clean kernels: every pipe <=55% busy, dur pinned
// 33.2us across direct/LDS/swizzled variants. Last untested lever:
// per-block serial work (dispatch-cohort ramp amortization). v19/v20 tried
// this with exact cross-image vmcnt bookkeeping and crashed; here iteration
// boundaries are CONSERVATIVE: in-order vmcnt retirement makes iter-2's
// counted waits merely over-wait while iter-1's stores drain (correct by
// construction), and iter-2's prologue loads overlap that drain.
#define HW 512
#define OW 506

typedef float vf4 __attribute__((ext_vector_type(4)));

// 3 x global_load_dwordx4; "=&v" early-clobber (v15 fault fix).
#define LOAD_ROW(d0, d1, d2, addr, O0, O1, O2)                        \
    asm volatile("global_load_dwordx4 %0, %3, off offset:" #O0 "\n\t" \
                 "global_load_dwordx4 %1, %3, off offset:" #O1 "\n\t" \
                 "global_load_dwordx4 %2, %3, off offset:" #O2        \
                 : "=&v"(d0), "=&v"(d1), "=&v"(d2)                    \
                 : "v"(addr) : "memory")

// Counted wait; tied "+v" operands pin consumer FMAs after the waitcnt.
#define WAIT_ROW(d0, d1, d2, N)                                       \
    asm volatile("s_waitcnt vmcnt(" #N ")"                            \
                 : "+v"(d0), "+v"(d1), "+v"(d2))

template<int SH>
__device__ __forceinline__ void row_fma(int ir, const vf4 (&b)[3],
                                        const float (&wv)[49],
                                        float (&acc)[32]) {
#pragma unroll
    for (int kr = 0; kr < 7; ++kr) {
        const int s = ir - kr;               // constant after caller unroll
        if (s >= 0 && s < 8) {
#pragma unroll
            for (int kc = 0; kc < 7; ++kc) {
                const float wk = wv[kr * 7 + kc];
#pragma unroll
                for (int j = 0; j < 4; ++j) {
                    const int e = SH + kc + j;          // 0..11, constant
                    acc[s * 4 + j] = fmaf(wk, b[e >> 2][e & 3], acc[s * 4 + j]);
                }
            }
        }
    }
}

template<int SH>
__device__ __forceinline__ void conv_pipe(const float* __restrict__ p0,
                                          const float (&wv)[49],
                                          float (&acc)[32]) {
    vf4 buf[4][3];                            // 4-row rotating buffer
    const float* a0 = p0;
    const float* a1 = p0 + 2 * HW;
    const float* a2 = p0 + 4 * HW;
    const float* a3 = p0 + 6 * HW;
    const float* a4 = p0 + 8 * HW;
    const float* a5 = p0 + 10 * HW;
    const float* a6 = p0 + 12 * HW;

    // prologue: rows 0..3 -> 12 loads in flight
    LOAD_ROW(buf[0][0], buf[0][1], buf[0][2], a0, 0, 16, 32);
    LOAD_ROW(buf[1][0], buf[1][1], buf[1][2], a0, 2048, 2064, 2080);
    LOAD_ROW(buf[2][0], buf[2][1], buf[2][2], a1, 0, 16, 32);
    LOAD_ROW(buf[3][0], buf[3][1], buf[3][2], a1, 2048, 2064, 2080);

    WAIT_ROW(buf[0][0], buf[0][1], buf[0][2], 9);
    row_fma<SH>(0, buf[0], wv, acc);
    LOAD_ROW(buf[0][0], buf[0][1], buf[0][2], a2, 0, 16, 32);        // row 4

    WAIT_ROW(buf[1][0], buf[1][1], buf[1][2], 9);
    row_fma<SH>(1, buf[1], wv, acc);
    LOAD_ROW(buf[1][0], buf[1][1], buf[1][2], a2, 2048, 2064, 2080); // row 5

    WAIT_ROW(buf[2][0], buf[2][1], buf[2][2], 9);
    row_fma<SH>(2, buf[2], wv, acc);
    LOAD_ROW(buf[2][0], buf[2][1], buf[2][2], a3, 0, 16, 32);        // row 6

    WAIT_ROW(buf[3][0], buf[3][1], buf[3][2], 9);
    row_fma<SH>(3, buf[3], wv, acc);
    LOAD_ROW(buf[3][0], buf[3][1], buf[3][2], a3, 2048, 2064, 2080); // row 7

    WAIT_ROW(buf[0][0], buf[0][1], buf[0][2], 9);
    row_fma<SH>(4, buf[0], wv, acc);
    LOAD_ROW(buf[0][0], buf[0][1], buf[0][2], a4, 0, 16, 32);        // row 8

    WAIT_ROW(buf[1][0], buf[1][1], buf[1][2], 9);
    row_fma<SH>(5, buf[1], wv, acc);
    LOAD_ROW(buf[1][0], buf[1][1], buf[1][2], a4, 2048, 2064, 2080); // row 9

    WAIT_ROW(buf[2][0], buf[2][1], buf[2][2], 9);
    row_fma<SH>(6, buf[2], wv, acc);
    LOAD_ROW(buf[2][0], buf[2][1], buf[2][2], a5, 0, 16, 32);        // row 10

    WAIT_ROW(buf[3][0], buf[3][1], buf[3][2], 9);
    row_fma<SH>(7, buf[3], wv, acc);
    LOAD_ROW(buf[3][0], buf[3][1], buf[3][2], a5, 2048, 2064, 2080); // row 11

    WAIT_ROW(buf[0][0], buf[0][1], buf[0][2], 9);
    row_fma<SH>(8, buf[0], wv, acc);
    LOAD_ROW(buf[0][0], buf[0][1], buf[0][2], a6, 0, 16, 32);        // row 12

    WAIT_ROW(buf[1][0], buf[1][1], buf[1][2], 9);
    row_fma<SH>(9, buf[1], wv, acc);
    LOAD_ROW(buf[1][0], buf[1][1], buf[1][2], a6, 2048, 2064, 2080); // row 13

    // epilogue: drain 9 -> 6 -> 3 -> 0
    WAIT_ROW(buf[2][0], buf[2][1], buf[2][2], 9);
    row_fma<SH>(10, buf[2], wv, acc);
    WAIT_ROW(buf[3][0], buf[3][1], buf[3][2], 6);
    row_fma<SH>(11, buf[3], wv, acc);
    WAIT_ROW(buf[0][0], buf[0][1], buf[0][2], 3);
    row_fma<SH>(12, buf[0], wv, acc);
    WAIT_ROW(buf[1][0], buf[1][1], buf[1][2], 0);
    row_fma<SH>(13, buf[1], wv, acc);
}

template<int SH>
__device__ __forceinline__ void do_tile(const float* __restrict__ p0,
                                        float* __restrict__ orow0,
                                        const float (&wv)[49], float bv) {
    float acc[32];
#pragma unroll
    for (int i = 0; i < 32; ++i) acc[i] = bv;   // bias folded into init

    conv_pipe<SH>(p0, wv, acc);

#pragma unroll
    for (int s = 0; s < 8; ++s) {
        float* orow = orow0 + (size_t)s * OW;   // 8B aligned (cb even)
        *reinterpret_cast<float2*>(orow) =
            make_float2(acc[s * 4 + 0], acc[s * 4 + 1]);
        *reinterpret_cast<float2*>(orow + 2) =
            make_float2(acc[s * 4 + 2], acc[s * 4 + 3]);
    }
}

__global__ __launch_bounds__(256) void conv7x7_v24(
    const float* __restrict__ in,      // [64][512][512]
    const float* __restrict__ weight,  // [7][7]
    const float* __restrict__ bias,    // [1]
    float* __restrict__ out)           // [64][506][506]
{
    const int tid  = threadIdx.x;
    const int lane = tid & 63;
    const int w    = tid >> 6;
    const int bx   = blockIdx.x;                // 0 or 1
    const int x0   = bx ? 250 : 0;              // tiles cover 0..255, 250..505
    const int y0   = min((int)blockIdx.y * 32, OW - 32);  // shifted last tile
    const int yb   = y0 + w * 8;                // wave's first output row (<=498)
    const int b2i  = blockIdx.z * 2;            // 2 images per block

    // ---- weights + bias -> SGPRs (uniform, statically indexed) ----
    float wv[49];
#pragma unroll
    for (int i = 0; i < 49; ++i)
        wv[i] = __uint_as_float(__builtin_amdgcn_readfirstlane(__float_as_uint(weight[i])));
    const float bv = __uint_as_float(__builtin_amdgcn_readfirstlane(__float_as_uint(bias[0])));

    const int cb = x0 + 4 * lane;               // first output col (<=502)
    const int off_in  = yb * HW + (cb - (bx ? 2 : 0));  // 16B-aligned base
    const int off_out = yb * OW + cb;

    const float* p0 = in  + (size_t)b2i * (HW * HW) + off_in;
    float*       o0 = out + (size_t)b2i * (OW * OW) + off_out;

    // ---- 2 images, sequential; iter-2's counted waits are conservative
    // across iter-1's outstanding stores (in-order vmcnt retirement) ----
    if (bx == 0) {
        do_tile<0>(p0, o0, wv, bv);
        do_tile<0>(p0 + HW * HW, o0 + OW * OW, wv, bv);
    } else {
        do_tile<2>(p0, o0, wv, bv);
        do_tile<2>(p0 + HW * HW, o0 + OW * OW, wv, bv);
    }
}

extern "C" void kernel_launch(void* const* d_in, const int* in_sizes, int n_in,
                              void* d_out, int out_size, void* d_ws, size_t ws_size,
                              hipStream_t stream) {
    const float* enc_x  = (const float*)d_in[0];
    const float* weight = (const float*)d_in[1];
    const float* bias   = (const float*)d_in[2];
    float* outp         = (float*)d_out;

    // x: 2 overlapping 256-col tiles; y: 16 tiles of 32 rows (last shifted);
    // z: 32 blocks x 2 sequential images. 1024 blocks = 4/CU.
    dim3 grid(2, 16, 32);
    dim3 block(256);
    hipLaunchKernelGGL(conv7x7_v24, grid, block, 0, stream,
                       enc_x, weight, bias, outp);
}

// Round 25
// 31.138 us; speedup vs baseline: 1.0723x; 1.0719x over previous
//
#include <hip/hip_runtime.h>

// B=64, H=W=512, K=7, VALID conv -> 506x506.
// v25: row-streaming slide. Model: per-CU TA line-touch rate (~3.5 cyc/line)
// binds all register-direct variants (v17: 25.6K lines/CU -> 37us ~ obs).
// Wave = 4 cols x 32 rows (38 in-rows / 32 out-rows: y-halo 1.75x -> 1.19x),
// 8-slot rotating acc (<=7 pending rows), stores spread in-loop.
// v17's proven asm engine: 4-row rotating buffer, counted vmcnt(9), 12 loads
// in flight. Interleaved C++ stores keep counted waits CORRECT by in-order
// vmcnt retirement (wait drains 3+s oldest >= target row's 3 loads).
// 2048 waves = 2/SIMD: ILP (MLP-12, 4-row lead ~1800cyc wall) covers latency.
#define HW 512
#define OW 506

typedef float vf4 __attribute__((ext_vector_type(4)));

// 3 x global_load_dwordx4; "=&v" early-clobber (v15 fault fix).
#define LOAD_ROW(d0, d1, d2, addr)                                    \
    asm volatile("global_load_dwordx4 %0, %3, off\n\t"                \
                 "global_load_dwordx4 %1, %3, off offset:16\n\t"      \
                 "global_load_dwordx4 %2, %3, off offset:32"          \
                 : "=&v"(d0), "=&v"(d1), "=&v"(d2)                    \
                 : "v"(addr) : "memory")

// Counted wait; tied "+v" operands pin consumer FMAs after the waitcnt.
#define WAIT_ROW(d0, d1, d2, N)                                       \
    asm volatile("s_waitcnt vmcnt(" #N ")"                            \
                 : "+v"(d0), "+v"(d1), "+v"(d2))

// Input row with phase r7 = r&7 contributes to outputs s = r-kr,
// slot s&7 = (r7-kr)&7. All indices constant after caller unroll.
template<int SH>
__device__ __forceinline__ void step_fma(int r7, int krlo, int krhi,
                                         const vf4 (&b)[3],
                                         const float (&wv)[49],
                                         float (&acc)[8][4]) {
#pragma unroll
    for (int kr = 0; kr < 7; ++kr) {
        if (kr >= krlo && kr <= krhi) {
            const int slot = (r7 - kr) & 7;
#pragma unroll
            for (int kc = 0; kc < 7; ++kc) {
                const float wk = wv[kr * 7 + kc];
#pragma unroll
                for (int j = 0; j < 4; ++j) {
                    const int e = SH + kc + j;          // 0..11, constant
                    acc[slot][j] = fmaf(wk, b[e >> 2][e & 3], acc[slot][j]);
                }
            }
        }
    }
}

#define STORE_SLOT(orow, S)                                           \
    {                                                                 \
        *reinterpret_cast<float2*>(orow) =                            \
            make_float2(acc[S][0], acc[S][1]);                        \
        *reinterpret_cast<float2*>((orow) + 2) =                      \
            make_float2(acc[S][2], acc[S][3]);                        \
        acc[S][0] = bv; acc[S][1] = bv; acc[S][2] = bv; acc[S][3] = bv; \
    }

template<int SH>
__device__ __forceinline__ void conv_band(const float* __restrict__ p0,
                                          float* __restrict__ ob,
                                          const float (&wv)[49], float bv) {
    vf4 buf[4][3];                 // 4-row rotating buffer (48 VGPR)
    float acc[8][4];               // 8-slot rotating accumulator
#pragma unroll
    for (int i = 0; i < 8; ++i)
#pragma unroll
        for (int j = 0; j < 4; ++j) acc[i][j] = bv;

    const float* ap = p0;          // next row to load

    // ---- prologue: rows 0..3 -> 12 loads in flight ----
    LOAD_ROW(buf[0][0], buf[0][1], buf[0][2], ap); ap += HW;
    LOAD_ROW(buf[1][0], buf[1][1], buf[1][2], ap); ap += HW;
    LOAD_ROW(buf[2][0], buf[2][1], buf[2][2], ap); ap += HW;
    LOAD_ROW(buf[3][0], buf[3][1], buf[3][2], ap); ap += HW;

    // ---- warmup rows 0..5 (no completed outputs yet) ----
#pragma unroll
    for (int r = 0; r < 6; ++r) {
        const int s3 = r & 3;
        WAIT_ROW(buf[s3][0], buf[s3][1], buf[s3][2], 9);
        step_fma<SH>(r & 7, 0, r, buf[s3], wv, acc);
        LOAD_ROW(buf[s3][0], buf[s3][1], buf[s3][2], ap); ap += HW;  // r+4
    }

    // ---- steady: rows 6..29, one output row completed per step ----
    float* op = ob;
#pragma unroll 1
    for (int g = 0; g < 3; ++g) {
#pragma unroll
        for (int k = 0; k < 8; ++k) {           // input row r = 8g+6+k
            const int s3 = (6 + k) & 3;
            const int r7 = (6 + k) & 7;
            WAIT_ROW(buf[s3][0], buf[s3][1], buf[s3][2], 9);
            step_fma<SH>(r7, 0, 6, buf[s3], wv, acc);
            STORE_SLOT(op + k * OW, k);         // output row 8g+k, slot k
            LOAD_ROW(buf[s3][0], buf[s3][1], buf[s3][2], ap); ap += HW; // r+4
        }
        op += 8 * OW;
    }
    // op now at output row 24

    // ---- tail rows 30..37 (loads until row 37; drain 9->6->3->0) ----
    WAIT_ROW(buf[2][0], buf[2][1], buf[2][2], 9);          // r=30
    step_fma<SH>(6, 0, 6, buf[2], wv, acc);
    STORE_SLOT(op + 0 * OW, 0);
    LOAD_ROW(buf[2][0], buf[2][1], buf[2][2], ap); ap += HW;  // row 34

    WAIT_ROW(buf[3][0], buf[3][1], buf[3][2], 9);          // r=31
    step_fma<SH>(7, 0, 6, buf[3], wv, acc);
    STORE_SLOT(op + 1 * OW, 1);
    LOAD_ROW(buf[3][0], buf[3][1], buf[3][2], ap); ap += HW;  // row 35

    WAIT_ROW(buf[0][0], buf[0][1], buf[0][2], 9);          // r=32
    step_fma<SH>(0, 1, 6, buf[0], wv, acc);
    STORE_SLOT(op + 2 * OW, 2);
    LOAD_ROW(buf[0][0], buf[0][1], buf[0][2], ap); ap += HW;  // row 36

    WAIT_ROW(buf[1][0], buf[1][1], buf[1][2], 9);          // r=33
    step_fma<SH>(1, 2, 6, buf[1], wv, acc);
    STORE_SLOT(op + 3 * OW, 3);
    LOAD_ROW(buf[1][0], buf[1][1], buf[1][2], ap); ap += HW;  // row 37

    WAIT_ROW(buf[2][0], buf[2][1], buf[2][2], 9);          // r=34
    step_fma<SH>(2, 3, 6, buf[2], wv, acc);
    STORE_SLOT(op + 4 * OW, 4);

    WAIT_ROW(buf[3][0], buf[3][1], buf[3][2], 6);          // r=35
    step_fma<SH>(3, 4, 6, buf[3], wv, acc);
    STORE_SLOT(op + 5 * OW, 5);

    WAIT_ROW(buf[0][0], buf[0][1], buf[0][2], 3);          // r=36
    step_fma<SH>(4, 5, 6, buf[0], wv, acc);
    STORE_SLOT(op + 6 * OW, 6);

    WAIT_ROW(buf[1][0], buf[1][1], buf[1][2], 0);          // r=37
    step_fma<SH>(5, 6, 6, buf[1], wv, acc);
    STORE_SLOT(op + 7 * OW, 7);
}

__global__ __launch_bounds__(256) void conv7x7_v25(
    const float* __restrict__ in,      // [64][512][512]
    const float* __restrict__ weight,  // [7][7]
    const float* __restrict__ bias,    // [1]
    float* __restrict__ out)           // [64][506][506]
{
    const int tid  = threadIdx.x;
    const int lane = tid & 63;
    const int w    = tid >> 6;
    const int bx   = blockIdx.x;                // 0 or 1
    const int x0   = bx ? 250 : 0;              // col strips 0..255 / 250..505
    const int y0   = 126 * blockIdx.y;          // bands 0,126,252,378
    const int yb   = y0 + 32 * w;               // wave's first output row (<=474)
    const int b    = blockIdx.z;

    // ---- weights + bias -> SGPRs (uniform, statically indexed) ----
    float wv[49];
#pragma unroll
    for (int i = 0; i < 49; ++i)
        wv[i] = __uint_as_float(__builtin_amdgcn_readfirstlane(__float_as_uint(weight[i])));
    const float bv = __uint_as_float(__builtin_amdgcn_readfirstlane(__float_as_uint(bias[0])));

    const int cb  = x0 + 4 * lane;              // first output col (<=502)
    const int cbl = cb - (bx ? 2 : 0);          // 16B-aligned window base
    // Bounds: rows yb..yb+37 <= 511 (474+37=511); cols cbl..cbl+11 <= 511.
    const float* p0 = in + (size_t)b * (HW * HW) + (size_t)yb * HW + cbl;
    float*       ob = out + (size_t)b * (OW * OW) + (size_t)yb * OW + cb;

    if (bx == 0) conv_band<0>(p0, ob, wv, bv);  // uniform SGPR branch
    else         conv_band<2>(p0, ob, wv, bv);
}

extern "C" void kernel_launch(void* const* d_in, const int* in_sizes, int n_in,
                              void* d_out, int out_size, void* d_ws, size_t ws_size,
                              hipStream_t stream) {
    const float* enc_x  = (const float*)d_in[0];
    const float* weight = (const float*)d_in[1];
    const float* bias   = (const float*)d_in[2];
    float* outp         = (float*)d_out;

    // x: 2 overlapping 256-col strips; y: 4 bands of 128 rows (4 waves x 32,
    // bands at 0/126/252/378 cover 506 with identical-overlap); z: 64 images.
    // 512 blocks = 2/CU, all co-resident (single cohort).
    dim3 grid(2, 4, 64);
    dim3 block(256);
    hipLaunchKernelGGL(conv7x7_v25, grid, block, 0, stream,
                       enc_x, weight, bias, outp);
}